// Round 15
// baseline (369.778 us; speedup 1.0000x reference)
//
#include <hip/hip_runtime.h>
#include <math.h>

#define NB 4096
#define NN 22
#define NE 42
#define DD 128
#define ED2 32
#define HH 128     // 4*ED
#define FF 2048
#define HCHUNKS 32 // FF/64

typedef float f32x4 __attribute__((ext_vector_type(4)));
typedef short s16x8 __attribute__((ext_vector_type(8)));

__device__ __forceinline__ float sigmoidf_(float x){ return 1.f/(1.f+__expf(-x)); }

__device__ __forceinline__ unsigned short f2bf(float f){
  unsigned u = __float_as_uint(f);
  u += 0x7fffu + ((u >> 16) & 1u);
  return (unsigned short)(u >> 16);
}
__device__ __forceinline__ float bf2f(unsigned short h){
  return __uint_as_float(((unsigned)h) << 16);
}
// gelu(x) = x*p/(p+1) = x - x/(p+1), p = exp(1.5957691*(x+0.044715 x^3))
__device__ __forceinline__ float gelu_f(float x){
  float x2 = x*x;
  float inner = fmaf(0.044715f*x2, x, x);
  float p = __builtin_amdgcn_exp2f(2.3022085f*inner);
  float t = __builtin_amdgcn_rcpf(p + 1.f);
  return fmaf(-x, t, x);
}

// ---- async global->LDS staging (zero VGPR footprint) ----
__device__ __forceinline__ void gld16(const void* g, void* l){
  __builtin_amdgcn_global_load_lds((__attribute__((address_space(1))) void*)g,
                                   (__attribute__((address_space(3))) void*)l, 16, 0, 0);
}
// stage BYTES from gbase to lbase; NW waves; BYTES % (NW*1024) == 0
template<int BYTES, int NW>
__device__ __forceinline__ void stage_lds(void* lbase, const void* gbase, int wave, int lane){
  const int per = BYTES / NW;
  const int ni  = per / 1024;
  const char* g = (const char*)gbase + wave*per + lane*16;
  char* l = (char*)lbase + wave*per;
  #pragma unroll
  for (int i=0;i<ni;i++) gld16(g + i*1024, l + i*1024);
}

#define S_VMCNT(N) { asm volatile("s_waitcnt vmcnt(" #N ")" ::: "memory"); __builtin_amdgcn_sched_barrier(0); }
#define S_LGKM0()  { asm volatile("s_waitcnt lgkmcnt(0)" ::: "memory"); __builtin_amdgcn_sched_barrier(0); }
#define RAW_BAR()  { asm volatile("s_waitcnt lgkmcnt(0)" ::: "memory"); __builtin_amdgcn_sched_barrier(0); __builtin_amdgcn_s_barrier(); __builtin_amdgcn_sched_barrier(0); }

// fragment-major index (u16 units) within a [C cols][128 k] bf16 tile
__device__ __forceinline__ int fragidx128(int c, int k){
  return ((c>>4)*4 + (k>>5))*512 + (((k>>3)&3)*16 + (c&15))*8 + (k&7);
}
__device__ __forceinline__ int fragidx64(int c, int k){  // k in [0,64)
  return ((c>>4)*2 + (k>>5))*512 + (((k>>3)&3)*16 + (c&15))*8 + (k&7);
}

// ---------------- K0: weight prep (fp32 -> bf16, fragment-major) ----------------
__global__ __launch_bounds__(256) void wconv_kernel(
    const float* __restrict__ fw1, const float* __restrict__ fw2,
    const float* __restrict__ ew1, const float* __restrict__ ew2,
    const float* __restrict__ rw, const float* __restrict__ uw, const float* __restrict__ cw,
    const float* __restrict__ pw, const float* __restrict__ aggm,
    unsigned short* __restrict__ w1t, unsigned short* __restrict__ w2b,
    unsigned short* __restrict__ ewc, unsigned short* __restrict__ ew2c,
    unsigned short* __restrict__ gw,
    unsigned short* __restrict__ tailf, unsigned short* __restrict__ pwf,
    unsigned short* __restrict__ aggmf)
{
  const int idx = blockIdx.x*256 + threadIdx.x;   // 0..262143
  {
    // fw1 [128][2048]; hidden-col permutation so ffn mm1 output (cg,nt,q,reg)
    // IS hidden unit h = cg*32 + q*8 + nt*4 + reg (within each 64-block).
    // Storage col jd fields: cg=bit5, nt=bit4, q=bits3..2, reg=bits1..0.
    const int k = idx >> 11, jd = idx & 2047;
    const int cl = jd & 63;
    const int jsrc = (jd & ~63) | (cl & 32) | (((cl>>2)&3)<<3) | (((cl>>4)&1)<<2) | (cl&3);
    w1t[(jd>>7)*16384 + fragidx128(jd&127, k)] = f2bf(fw1[k*2048 + jsrc]);
  }
  {
    const int kg = idx >> 7, c = idx & 127;       // fw2 [2048][128] -> 16KB half-chunks (64 k rows)
    w2b[(kg>>6)*8192 + fragidx64(c, kg&63)] = f2bf(fw2[idx]);
  }
  if (idx < 32768) {
    // ewc2: k-major 16KB chunks: part (src/tgt) x khalf contiguous
    const int c2 = idx >> 7, k = idx & 127;
    const int part = c2 >> 7, c = c2 & 127;
    const float v = ew1[(part*128 + k)*DD + c];
    ewc[part*16384 + ((k>>5)*8 + (c>>4))*512 + (((k>>3)&3)*16 + (c&15))*8 + (k&7)] = f2bf(v);
  }
  if (idx < 4096) {
    const int m = idx & 31, k = idx >> 5;         // ew2 [128][32]
    ew2c[fragidx128(m, k)] = f2bf(ew2[k*ED2 + m]);
  }
  if (idx < 4096) {
    // tailf / pwf: B-frag [32 k][128 c], single k-step
    const int k = idx >> 7, c = idx & 127;
    const int u = (c>>4)*512 + ((k>>3)*16 + (c&15))*8 + (k&7);
    tailf[u] = f2bf(ew1[(256 + k)*DD + c]);
    pwf[u]  = f2bf(pw[k*DD + c]);
  }
  if (idx < 2048) {
    // aggmf: A-frag [32 n][64 e], zero-padded
    const int n = idx >> 6, e = idx & 63;
    const float v = (n < NN && e < NE) ? aggm[n*NE + e] : 0.f;
    aggmf[(n>>4)*1024 + (e>>5)*512 + (((e>>3)&3)*16 + (n&15))*8 + (e&7)] = f2bf(v);
  }
  if (idx < 98304) {
    const int gate = idx >> 15;
    const int rem  = idx & 32767;
    const int half = rem >> 14, c = (rem >> 7) & 127, k = rem & 127;
    const float* wsrc = (gate==0) ? rw : ((gate==1) ? uw : cw);
    const float v = wsrc[(half*128 + k)*128 + c];
    gw[gate*32768 + half*16384 + (k>>6)*8192 + fragidx64(c, k&63)] = f2bf(v);
  }
}

// ---------------- K1: all-MFMA edge path, 2 batches/block, 74.4KB LDS -> 2 blocks/CU ----------------
__global__ __launch_bounds__(512) void edge_mfma_kernel(
    const float* __restrict__ nf, const float* __restrict__ ea,
    const int* __restrict__ src, const int* __restrict__ tgt,
    const float* __restrict__ eb1, const float* __restrict__ eb2,
    const float* __restrict__ pb,
    const unsigned short* __restrict__ ewc2,
    const unsigned short* __restrict__ ew2c,
    const unsigned short* __restrict__ tailf,
    const unsigned short* __restrict__ pwf,
    const unsigned short* __restrict__ aggmf,
    const float* __restrict__ g1, const float* __restrict__ be1,
    float* __restrict__ out_em, float* __restrict__ out_x)
{
  const int t = threadIdx.x, lane = t & 63, wave = t >> 6;
  const int wv = wave & 3;               // intra-batch wave
  const int bb = wave >> 2;              // batch half
  const int b  = blockIdx.x*2 + bb;
  const int th = t & 255;                // intra-batch thread id

  __shared__ __align__(16) char s_lds[76160];
  unsigned short* s_w0  = (unsigned short*)(s_lds);            // 16KB ping (shared); pw here in em+
  unsigned short* s_w1  = (unsigned short*)(s_lds + 16384);    // 16KB pong (shared)
  unsigned short* s_emf = (unsigned short*)(s_lds + 16384 + bb*4096);  // 4KB/batch (overlay on s_w1)
  unsigned short* s_ew2 = (unsigned short*)(s_lds + 32768);    // 8KB (shared)
  unsigned short* s_agm = (unsigned short*)(s_lds + 40960);    // 4KB (shared)
  char*           s_a   = s_lds + 45056 + bb*8192;             // 8KB/batch (rounds 0-3)
  char*           s_h   = s_lds + 45056 + bb*12288;            // 12KB/batch (round4..em; then proj rows)
  unsigned short* s_eaf = (unsigned short*)(s_lds + 69632 + bb*3072);  // 3KB/batch
  unsigned short* s_agf = s_eaf;                               // 2KB overlay (eaf dead after round 4)
  int*            s_srcA= (int*)(s_lds + 75776);               // 48 ints (shared)
  int*            s_tgtA= (int*)(s_lds + 75968);               // 48 ints (shared)

  // ---- issue weight stages (ewc chunk0 + ew2 + agm), all waves ----
  stage_lds<16384,8>(s_w0, ewc2, wave, lane);
  stage_lds<8192,8>(s_ew2, ew2c, wave, lane);
  if (wave < 4) stage_lds<4096,4>(s_agm, aggmf, wave, lane);

  // ---- LN1 -> s_a bf16 XOR layout (rows 22..31 zero), per batch ----
  for (int r = wv; r < NN; r += 4) {
    const float* row = nf + ((size_t)b*NN + r)*DD;
    float x0 = row[lane], x1 = row[lane+64];
    float s = x0+x1, ss = x0*x0+x1*x1;
    #pragma unroll
    for (int off=32; off>=1; off>>=1) { s += __shfl_xor(s,off); ss += __shfl_xor(ss,off); }
    float m = s*(1.f/128.f);
    float inv = rsqrtf(ss*(1.f/128.f)-m*m + 1e-5f);
    float n0 = (x0-m)*inv*g1[lane]+be1[lane];
    float n1 = (x1-m)*inv*g1[lane+64]+be1[lane+64];
    char* base = s_a + r*256;
    const int sw = (r&7)<<4;
    *(unsigned short*)(base + ((lane*2)      ^ sw)) = f2bf(n0);
    *(unsigned short*)(base + (((lane+64)*2) ^ sw)) = f2bf(n1);
  }
  for (int i=th; i<640; i+=256) ((float*)(s_a + NN*256))[i] = 0.f;

  if (t < 48) { s_srcA[t] = (t < NE) ? src[t] : NN; s_tgtA[t] = (t < NE) ? tgt[t] : NN; }

  // ---- ea -> A-frag bf16 (rows 42..47 zero), per batch ----
  if (th < 168) {
    const int e = th >> 2, kb = th & 3;
    const float* p = ea + ((size_t)b*NE + e)*ED2 + kb*8;
    const float4 v0 = *(const float4*)p;
    const float4 v1 = *(const float4*)(p+4);
    unsigned long long lo = (unsigned long long)f2bf(v0.x) | ((unsigned long long)f2bf(v0.y)<<16)
                          | ((unsigned long long)f2bf(v0.z)<<32) | ((unsigned long long)f2bf(v0.w)<<48);
    unsigned long long hi = (unsigned long long)f2bf(v1.x) | ((unsigned long long)f2bf(v1.y)<<16)
                          | ((unsigned long long)f2bf(v1.z)<<32) | ((unsigned long long)f2bf(v1.w)<<48);
    unsigned long long* dst = (unsigned long long*)(s_eaf + (e>>4)*512 + (kb*16 + (e&15))*8);
    dst[0] = lo; dst[1] = hi;
  } else if (th < 192) {
    const int idx = th - 168;              // 0..23: zero rows 42..47
    const int kb = idx / 6, er = 10 + idx % 6;
    unsigned long long* dst = (unsigned long long*)(s_eaf + 2*512 + (kb*16 + er)*8);
    dst[0] = 0ull; dst[1] = 0ull;
  }

  __syncthreads();   // full drain (vmcnt+lgkm in every wave): s_w0 and all stages ready

  // ---- h = relu(gather(src)@Wsrc + gather(tgt)@Wtgt + ea@Wtail + eb1) ----
  const int frow = lane & 15;
  const int gsel = (lane >> 4) << 4;            // lane's 16B k-slot
  const int nt0 = wv*2;

  int rowS[3], rowT[3];
  #pragma unroll
  for (int mt=0; mt<3; ++mt){
    rowS[mt] = s_srcA[mt*16 + frow];
    rowT[mt] = s_tgtA[mt*16 + frow];
  }

  f32x4 hacc[3][2];
  #pragma unroll
  for (int mt=0; mt<3; ++mt){
    hacc[mt][0] = (f32x4){0.f,0.f,0.f,0.f};
    hacc[mt][1] = (f32x4){0.f,0.f,0.f,0.f};
  }

  #define HROUND(WCP, ROWS, KOFF) { \
    const unsigned short* wc_ = (WCP); \
    _Pragma("unroll") \
    for (int mt=0; mt<3; ++mt){ \
      const int r_ = (ROWS)[mt]; \
      const int sw_ = (r_&7)<<4; \
      const s16x8 a0 = *(const s16x8*)(s_a + r_*256 + (((KOFF) + gsel)^sw_)); \
      const s16x8 a1 = *(const s16x8*)(s_a + r_*256 + (((KOFF) + 64 + gsel)^sw_)); \
      _Pragma("unroll") \
      for (int ntl=0; ntl<2; ++ntl){ \
        const s16x8 b0 = *(const s16x8*)(wc_ + (    nt0+ntl)*512 + lane*8); \
        const s16x8 b1 = *(const s16x8*)(wc_ + (8 + nt0+ntl)*512 + lane*8); \
        hacc[mt][ntl] = __builtin_amdgcn_mfma_f32_16x16x32_bf16(a0, b0, hacc[mt][ntl], 0,0,0); \
        hacc[mt][ntl] = __builtin_amdgcn_mfma_f32_16x16x32_bf16(a1, b1, hacc[mt][ntl], 0,0,0); \
      } \
    } }

  // round 0: compute src k0..63 (s_w0); stage s_w1 overlapped, drain before BAR
  stage_lds<16384,8>(s_w1, ewc2 + 8192, wave, lane);
  HROUND(s_w0, rowS, 0);
  S_VMCNT(0);
  RAW_BAR();
  // round 1: src k64..127
  stage_lds<16384,8>(s_w0, ewc2 + 16384, wave, lane);
  HROUND(s_w1, rowS, 128);
  S_VMCNT(0);
  RAW_BAR();
  // round 2: tgt k0..63
  stage_lds<16384,8>(s_w1, ewc2 + 24576, wave, lane);
  HROUND(s_w0, rowT, 0);
  S_VMCNT(0);
  RAW_BAR();
  // round 3: tgt k64..127; stage tail (8KB) into s_w0
  stage_lds<8192,8>(s_w0, tailf, wave, lane);
  HROUND(s_w1, rowT, 128);
  S_VMCNT(0);
  RAW_BAR();   // after this bar: s_a dead (all HROUND reads done), s_h may be written
  #undef HROUND

  // round 4: ea@tail (s_w0 first 8KB) + zero both emf (s_w1 free) + h store
  { uint4 z; z.x=0u; z.y=0u; z.z=0u; z.w=0u; *(uint4*)(s_lds + 16384 + t*16) = z; }
  #pragma unroll
  for (int mt=0; mt<3; ++mt){
    const s16x8 ae = *(const s16x8*)(s_eaf + mt*512 + lane*8);
    #pragma unroll
    for (int ntl=0; ntl<2; ++ntl){
      const s16x8 bt = *(const s16x8*)(s_w0 + (nt0+ntl)*512 + lane*8);
      hacc[mt][ntl] = __builtin_amdgcn_mfma_f32_16x16x32_bf16(ae, bt, hacc[mt][ntl], 0,0,0);
    }
  }
  #pragma unroll
  for (int mt=0; mt<3; ++mt){
    #pragma unroll
    for (int ntl=0; ntl<2; ++ntl){
      const int c = (nt0+ntl)*16 + frow;
      const float e1 = eb1[c];
      #pragma unroll
      for (int reg=0; reg<4; ++reg){
        const int e = mt*16 + (lane>>4)*4 + reg;
        const float v = fmaxf(hacc[mt][ntl][reg] + e1, 0.f);
        *(unsigned short*)(s_h + e*256 + ((c*2) ^ ((e&7)<<4))) = (e < NE) ? f2bf(v) : (unsigned short)0;
      }
    }
  }
  RAW_BAR();   // after this bar: s_w0 dead (tail read done) -> pw restage target

  // ---- em = h @ ew2 + eb2 -> out_em (f32) + s_emf (B-frag bf16), per batch ----
  stage_lds<8192,8>(s_w0, pwf, wave, lane);
  for (int id = wv; id < 6; id += 4) {
    const int mt = id >> 1, ntn = id & 1;
    f32x4 acc2 = (f32x4){0.f,0.f,0.f,0.f};
    #pragma unroll
    for (int ks=0; ks<4; ++ks){
      const s16x8 av = *(const s16x8*)(s_h + (mt*16 + frow)*256 + ((ks*64 + gsel) ^ ((frow&7)<<4)));
      const s16x8 bv = *(const s16x8*)(s_ew2 + (ntn*4+ks)*512 + lane*8);
      acc2 = __builtin_amdgcn_mfma_f32_16x16x32_bf16(av, bv, acc2, 0,0,0);
    }
    const int mc = ntn*16 + frow;
    const float bias = eb2[mc];
    #pragma unroll
    for (int reg=0; reg<4; ++reg){
      const int e = mt*16 + (lane>>4)*4 + reg;
      if (e < NE) {
        const float v = acc2[reg] + bias;
        out_em[((size_t)b*NE + e)*ED2 + mc] = v;
        s_emf[(mc>>4)*1024 + (e>>5)*512 + (((e>>3)&3)*16 + (mc&15))*8 + (e&7)] = f2bf(v);
      }
    }
  }
  S_VMCNT(0);   // pw arrived in every wave
  RAW_BAR();    // s_h (em reads) done; emf visible

  // ---- agg = aggm @ em (K padded to 64) -> s_agf (A-frag bf16), per batch ----
  {
    const int mt = wv >> 1, ntn = wv & 1;
    f32x4 acc3 = (f32x4){0.f,0.f,0.f,0.f};
    #pragma unroll
    for (int ks=0; ks<2; ++ks){
      const s16x8 av = *(const s16x8*)(s_agm + (mt*2+ks)*512 + lane*8);
      const s16x8 bv = *(const s16x8*)(s_emf + (ntn*2+ks)*512 + lane*8);
      acc3 = __builtin_amdgcn_mfma_f32_16x16x32_bf16(av, bv, acc3, 0,0,0);
    }
    const int mc = ntn*16 + frow;
    #pragma unroll
    for (int reg=0; reg<4; ++reg){
      const int n = mt*16 + (lane>>4)*4 + reg;
      s_agf[(n>>4)*512 + (((mc>>3)&3)*16 + (n&15))*8 + (mc&7)] = f2bf(acc3[reg]);
    }
  }
  RAW_BAR();

  // ---- proj = agg @ pw + pb -> s_h rows (bf16, swizzled), per batch ----
  const unsigned short* s_pw = (const unsigned short*)s_lds;   // pw now in s_w0
  #pragma unroll
  for (int ii=0; ii<4; ++ii){
    const int id = wv + ii*4;
    const int mt = id >> 3, nt = id & 7;
    const s16x8 av = *(const s16x8*)(s_agf + mt*512 + lane*8);
    const s16x8 bv = *(const s16x8*)(s_pw + nt*512 + lane*8);
    f32x4 a4 = __builtin_amdgcn_mfma_f32_16x16x32_bf16(av, bv, (f32x4){0.f,0.f,0.f,0.f}, 0,0,0);
    const int c = nt*16 + frow;
    const float pbv = pb[c];
    #pragma unroll
    for (int reg=0; reg<4; ++reg){
      const int n = mt*16 + (lane>>4)*4 + reg;
      *(unsigned short*)(s_h + n*256 + ((c*2) ^ ((n&7)<<4))) = f2bf(a4[reg] + pbv);
    }
  }
  RAW_BAR();

  // ---- pack proj rows into out_x fragment cells (16B stores), per batch ----
  for (int o=th; o<NN*16; o+=256){
    const int n = o>>4, cell = o&15;
    const int k0 = (cell>>2)*32 + (cell&3)*8;
    const uint4 v = *(const uint4*)(s_h + n*256 + ((k0*2) ^ ((n&7)<<4)));
    *(uint4*)((char*)out_x + (((size_t)b*NN + n)*512) + cell*16) = v;
  }
}

// ---------------- K2: gated update via MFMA, 48.6KB LDS -> 3 blocks/CU ----------------
__global__ __launch_bounds__(256) void gate_mfma_kernel(
    const float* __restrict__ nf,
    const float* __restrict__ rb, const float* __restrict__ ub, const float* __restrict__ cbv,
    const float* __restrict__ g1, const float* __restrict__ be1,
    const unsigned short* __restrict__ gw,
    float* __restrict__ out_x)
{
  const int t=threadIdx.x, lane=t&63, wave=t>>6;
  const size_t row0 = (size_t)blockIdx.x * 64;
  const int wrow = wave*16;

  __shared__ __align__(16) unsigned short s_nb[8192];    // frag-major normed; becomes rc
  __shared__ __align__(16) unsigned short s_w[2][8192];  // 2x16KB ping-pong
  __shared__ float s_mean[64], s_inv[64];
  unsigned short* s_pb = s_w[1];                         // proj frag overlay (dead after lift)

  const char* gwb = (const char*)gw;

  stage_lds<16384,4>(s_w[0], gwb, wave, lane);   // stage 0 (latency under LN/proj copy)

  // proj copy: per-row cells -> fragment-major s_pb (= s_w[1] region)
  for (int i=t; i<1024; i+=256){
    const int r = i>>4, cell = i&15;
    ((uint4*)s_pb)[((r>>4)*4 + (cell>>2))*64 + (cell&3)*16 + (r&15)] =
      *((const uint4*)(out_x + (row0+r)*DD) + cell);
  }

  // LN1 -> s_nb fragment-major
  for (int r16=0; r16<16; ++r16){
    const int row = wrow + r16;
    const float* xr = nf + (row0+row)*DD;
    float x0=xr[lane], x1=xr[lane+64];
    float s=x0+x1, ss=x0*x0+x1*x1;
    #pragma unroll
    for (int off=32; off>=1; off>>=1){ s+=__shfl_xor(s,off); ss+=__shfl_xor(ss,off); }
    float m=s*(1.f/128.f);
    float inv=rsqrtf(ss*(1.f/128.f)-m*m+1e-5f);
    if (lane==0){ s_mean[row]=m; s_inv[row]=inv; }
    float n0=(x0-m)*inv*g1[lane]+be1[lane];
    float n1=(x1-m)*inv*g1[lane+64]+be1[lane+64];
    const int mt = row>>4, fr = row&15;
    const int ks = lane>>5, g = (lane>>3)&3, j = lane&7;
    s_nb[(mt*4+ks)*512   + (g*16+fr)*8 + j] = f2bf(n0);
    s_nb[(mt*4+ks+2)*512 + (g*16+fr)*8 + j] = f2bf(n1);
  }
  __syncthreads();   // drains stage0 + LDS writes

  s16x8 aN[4], aP[4];
  #pragma unroll
  for (int kk=0; kk<4; ++kk){
    aN[kk] = *(const s16x8*)(s_nb + (wave*4+kk)*512 + lane*8);
    aP[kk] = *(const s16x8*)(s_pb + (wave*4+kk)*512 + lane*8);
  }
  RAW_BAR();   // aP/aN lifts complete in all waves before s_w[1] is restaged

  f32x4 accR[8], accU[8], accC[8];
  #pragma unroll
  for (int nt=0; nt<8; ++nt){
    const int col = nt*16 + (lane&15);
    accR[nt] = (f32x4){rb[col],rb[col],rb[col],rb[col]};
    accU[nt] = (f32x4){ub[col],ub[col],ub[col],ub[col]};
    accC[nt] = (f32x4){cbv[col],cbv[col],cbv[col],cbv[col]};
  }

  #define GSTAGE(S, NEXT, ACC, A0, A1) { \
    if (NEXT) stage_lds<16384,4>(s_w[((S)+1)&1], gwb + ((S)+1)*16384, wave, lane); \
    unsigned short* sb = s_w[(S)&1]; \
    _Pragma("unroll") for (int nt=0;nt<8;++nt){ \
      const s16x8 b0 = *(const s16x8*)(sb + (nt*2+0)*512 + lane*8); \
      ACC[nt] = __builtin_amdgcn_mfma_f32_16x16x32_bf16(A0, b0, ACC[nt], 0,0,0); \
      const s16x8 b1 = *(const s16x8*)(sb + (nt*2+1)*512 + lane*8); \
      ACC[nt] = __builtin_amdgcn_mfma_f32_16x16x32_bf16(A1, b1, ACC[nt], 0,0,0); } \
    S_VMCNT(0); \
    RAW_BAR(); }

  GSTAGE(0, 1, accR, aN[0], aN[1]);
  GSTAGE(1, 1, accR, aN[2], aN[3]);
  GSTAGE(2, 1, accR, aP[0], aP[1]);
  GSTAGE(3, 1, accR, aP[2], aP[3]);

  // rc = sigmoid(R)*normed, in-place in s_nb (own wave's rows only)
  #pragma unroll
  for (int nt=0; nt<8; ++nt){
    #pragma unroll
    for (int reg=0; reg<4; ++reg){
      const float r_ = sigmoidf_(accR[nt][reg]);
      const int frA = (lane>>4)*4 + reg;
      const int ks = nt>>1, g = ((nt&1)<<1) | ((lane&15)>>3), j = lane&7;
      unsigned short* p = s_nb + (wave*4+ks)*512 + (g*16+frA)*8 + j;
      *p = f2bf(r_ * bf2f(*p));
    }
  }
  s16x8 aRC[4];
  #pragma unroll
  for (int kk=0; kk<4; ++kk)
    aRC[kk] = *(const s16x8*)(s_nb + (wave*4+kk)*512 + lane*8);

  GSTAGE(4, 1, accU, aN[0], aN[1]);
  GSTAGE(5, 1, accU, aN[2], aN[3]);
  GSTAGE(6, 1, accU, aP[0], aP[1]);
  GSTAGE(7, 1, accU, aP[2], aP[3]);
  GSTAGE(8, 1, accC, aRC[0], aRC[1]);
  GSTAGE(9, 1, accC, aRC[2], aRC[3]);
  GSTAGE(10, 1, accC, aP[0], aP[1]);
  GSTAGE(11, 0, accC, aP[2], aP[3]);
  #undef GSTAGE

  // combine: x = nf + (1-u)*normed + u*cand
  #pragma unroll
  for (int nt=0; nt<8; ++nt){
    const int col = nt*16 + (lane&15);
    const float gg = g1[col], bb = be1[col];
    #pragma unroll
    for (int reg=0; reg<4; ++reg){
      const int rowl = wrow + (lane>>4)*4 + reg;
      const size_t grow = row0 + rowl;
      const float u_ = sigmoidf_(accU[nt][reg]);
      const float cand = tanhf(accC[nt][reg]);
      const float nfv = nf[grow*DD + col];
      const float nv = (nfv - s_mean[rowl])*s_inv[rowl]*gg + bb;
      out_x[grow*DD + col] = nfv + (1.f-u_)*nv + u_*cand;
    }
  }
}

// ---------------- K3: LN2 + FFN, M=128, in-register hid handoff, 64KB LDS ----------------
// W1 cols pre-permuted (wconv) so transposed mm1 output (cg,nt,q,reg) IS hidden
// unit h = cg*32+q*8+nt*4+reg: the cvt_pk'd registers {plo0,phi0,plo1,phi1} form
// mm2's A-fragment directly (zero LDS, zero mid barrier). Wave (rg,cg) accumulates
// mm2 partials over its own 32-k block for ALL 128 out cols; partner partials
// summed once at the epilogue via LDS exchange in the dead weight buffers.
// One barrier + vmcnt(0) drain per hc (barrier-safe discipline).
__global__ __launch_bounds__(512) void ffn_mfma_kernel(
    float* __restrict__ out_x,
    const float* __restrict__ g2, const float* __restrict__ be2,
    const float* __restrict__ fb1, const float* __restrict__ fb2,
    const unsigned short* __restrict__ w1t,
    const unsigned short* __restrict__ w2b)
{
  const int t = threadIdx.x, lane = t & 63, wave = t >> 6;
  const size_t row0 = (size_t)blockIdx.x * 128;
  const int wrow = wave * 16;
  const int rg = wave >> 1, cg = wave & 1;

  __shared__ __align__(16) unsigned short s_buf[2][16384];  // 2 x 32KB: [w1 16KB | w2 16KB]

  // prologue: stage buf0 = {w1[0], w2[0]}
  stage_lds<16384,8>(s_buf[0],        w1t, wave, lane);
  stage_lds<16384,8>(s_buf[0] + 8192, w2b, wave, lane);

  // LN2 -> buf1 (32KB free at prologue): mtile m written by wave m at
  // buf1 + (m>>2)*8192 + ((m&3)*4+ks)*512
  for (int r16 = 0; r16 < 16; ++r16) {
    const int row = wrow + r16;               // row>>4 == wave
    const float* xr = out_x + (row0+row)*DD;
    float x0 = xr[lane], x1 = xr[lane+64];
    float s = x0+x1, ss = x0*x0+x1*x1;
    #pragma unroll
    for (int off=32; off>=1; off>>=1){ s+=__shfl_xor(s,off); ss+=__shfl_xor(ss,off); }
    float m = s*(1.f/128.f);
    float inv = rsqrtf(ss*(1.f/128.f)-m*m+1e-5f);
    float n0 = (x0-m)*inv*g2[lane]+be2[lane];
    float n1 = (x1-m)*inv*g2[lane+64]+be2[lane+64];
    const int fr = row&15;
    const int ks = lane>>5, g = (lane>>3)&3, j = lane&7;
    unsigned short* dst = s_buf[1] + (wave>>2)*8192;
    const int wv = wave & 3;
    dst[(wv*4+ks)*512   + (g*16+fr)*8 + j] = f2bf(n0);
    dst[(wv*4+ks+2)*512 + (g*16+fr)*8 + j] = f2bf(n1);
  }
  __syncthreads();   // drains buf0 stage + LN LDS writes (cross-wave lift next)

  const int frow = lane & 15;
  const int q = lane >> 4;       // 0..3

  // lift aN for mtiles m = rg*2 + mt (cross-wave reads; safe after syncthreads)
  s16x8 aN[2][4];
  #pragma unroll
  for (int mt=0; mt<2; ++mt){
    const int m = rg*2 + mt;
    const unsigned short* srcb = s_buf[1] + (m>>2)*8192;
    #pragma unroll
    for (int ks=0; ks<4; ++ks)
      aN[mt][ks] = *(const s16x8*)(srcb + ((m&3)*4+ks)*512 + lane*8);
  }
  RAW_BAR();   // all waves' aN lifted before buf1 is restaged (hc=0 stages buf1)

  f32x4 accO[2][8];
  #pragma unroll
  for (int mt=0; mt<2; ++mt)
    #pragma unroll
    for (int nt=0; nt<8; ++nt)
      accO[mt][nt] = (f32x4){0.f,0.f,0.f,0.f};

  for (int hc = 0; hc < HCHUNKS; ++hc) {
    const unsigned short* cur = s_buf[hc & 1];
    unsigned short* nxt = s_buf[(hc + 1) & 1];
    if (hc < HCHUNKS-1) {
      stage_lds<16384,8>(nxt,        w1t + (hc+1)*8192, wave, lane);
      stage_lds<16384,8>(nxt + 8192, w2b + (hc+1)*8192, wave, lane);
    }

    // mm1 transposed: produced (nt,q,reg) = hidden h = cg*32 + q*8 + nt*4 + reg
    f32x4 acc1[2][2];
    #pragma unroll
    for (int nt=0; nt<2; ++nt){
      const float4 bv = *(const float4*)(fb1 + hc*64 + cg*32 + (q<<3) + (nt<<2));
      acc1[0][nt] = (f32x4){bv.x, bv.y, bv.z, bv.w};
      acc1[1][nt] = acc1[0][nt];
    }
    #pragma unroll
    for (int nt=0; nt<2; ++nt){
      #pragma unroll
      for (int ks=0; ks<4; ++ks){
        const s16x8 ww = *(const s16x8*)(cur + ((cg*2+nt)*4+ks)*512 + lane*8);
        acc1[0][nt] = __builtin_amdgcn_mfma_f32_16x16x32_bf16(ww, aN[0][ks], acc1[0][nt], 0,0,0);
        acc1[1][nt] = __builtin_amdgcn_mfma_f32_16x16x32_bf16(ww, aN[1][ks], acc1[1][nt], 0,0,0);
      }
    }
    // gelu -> in-register A-frag {plo0,phi0,plo1,phi1} (k = q*8 + nt*4 + reg)
    #pragma unroll
    for (int mt=0; mt<2; ++mt){
      uint4 hv;
      {
        const float e0 = gelu_f(acc1[mt][0][0]);
        const float e1 = gelu_f(acc1[mt][0][1]);
        const float e2 = gelu_f(acc1[mt][0][2]);
        const float e3 = gelu_f(acc1[mt][0][3]);
        unsigned plo, phi;
        asm("v_cvt_pk_bf16_f32 %0, %1, %2" : "=v"(plo) : "v"(e0), "v"(e1));
        asm("v_cvt_pk_bf16_f32 %0, %1, %2" : "=v"(phi) : "v"(e2), "v"(e3));
        hv.x = plo; hv.y = phi;
      }
      {
        const float e0 = gelu_f(acc1[mt][1][0]);
        const float e1 = gelu_f(acc1[mt][1][1]);
        const float e2 = gelu_f(acc1[mt][1][2]);
        const float e3 = gelu_f(acc1[mt][1][3]);
        unsigned plo, phi;
        asm("v_cvt_pk_bf16_f32 %0, %1, %2" : "=v"(plo) : "v"(e0), "v"(e1));
        asm("v_cvt_pk_bf16_f32 %0, %1, %2" : "=v"(phi) : "v"(e2), "v"(e3));
        hv.z = plo; hv.w = phi;
      }
      s16x8 aH;
      __builtin_memcpy(&aH, &hv, 16);
      // mm2 partial: own 32-k block (ks = cg), ALL 128 out cols
      #pragma unroll
      for (int nt=0; nt<8; ++nt){
        const s16x8 bb = *(const s16x8*)(cur + 8192 + (nt*2+cg)*512 + lane*8);
        accO[mt][nt] = __builtin_amdgcn_mfma_f32_16x16x32_bf16(aH, bb, accO[mt][nt], 0,0,0);
      }
    }
    S_VMCNT(0);   // nxt stage arrived in every wave (before the barrier)
    RAW_BAR();    // cur free for restage; nxt visible
  }

  // ---- epilogue: cross-wave k-partial reduction via dead weight buffers ----
  float* s_red = (float*)s_buf;   // 64KB
  {
    float* wr = s_red + rg*4096 + cg*2048;   // write partial for NON-owned cols
    #pragma unroll
    for (int mt=0; mt<2; ++mt){
      #pragma unroll
      for (int nl=0; nl<4; ++nl){
        const int nt = (cg==0) ? (4+nl) : nl;
        #pragma unroll
        for (int reg=0; reg<4; ++reg)
          wr[((mt*4+nl)*4+reg)*64 + lane] = accO[mt][nt][reg];
      }
    }
  }
  RAW_BAR();
  {
    const float* rd = s_red + rg*4096 + (1-cg)*2048;  // sibling partial for own cols
    #pragma unroll
    for (int mt=0; mt<2; ++mt){
      #pragma unroll
      for (int nl=0; nl<4; ++nl){
        const int nt = cg*4 + nl;
        const int colg = nt*16 + frow;
        const float bias = fb2[colg];
        #pragma unroll
        for (int reg=0; reg<4; ++reg){
          const size_t row = row0 + rg*32 + mt*16 + q*4 + reg;
          const float xo = out_x[row*DD + colg];
          out_x[row*DD + colg] = xo + bias + accO[mt][nt][reg]
                                 + rd[((mt*4+nl)*4+reg)*64 + lane];
        }
      }
    }
  }
}

extern "C" void kernel_launch(void* const* d_in, const int* in_sizes, int n_in,
                              void* d_out, int out_size, void* d_ws, size_t ws_size,
                              hipStream_t stream) {
  const float* nf  = (const float*)d_in[0];
  const float* ea  = (const float*)d_in[1];
  const float* agg = (const float*)d_in[2];
  const int*   src = (const int*)d_in[3];
  const int*   tgt = (const int*)d_in[4];
  const float* ew1 = (const float*)d_in[5];
  const float* eb1 = (const float*)d_in[6];
  const float* ew2 = (const float*)d_in[7];
  const float* eb2 = (const float*)d_in[8];
  const float* pw  = (const float*)d_in[9];
  const float* pb  = (const float*)d_in[10];
  const float* rw  = (const float*)d_in[11];
  const float* rb  = (const float*)d_in[12];
  const float* uw  = (const float*)d_in[13];
  const float* ub  = (const float*)d_in[14];
  const float* cw  = (const float*)d_in[15];
  const float* cbv = (const float*)d_in[16];
  const float* g1  = (const float*)d_in[17];
  const float* be1 = (const float*)d_in[18];
  const float* g2  = (const float*)d_in[19];
  const float* be2 = (const float*)d_in[20];
  const float* fw1 = (const float*)d_in[21];
  const float* fb1 = (const float*)d_in[22];
  const float* fw2 = (const float*)d_in[23];
  const float* fb2 = (const float*)d_in[24];

  float* out_x  = (float*)d_out;
  float* out_em = (float*)d_out + (size_t)NB*NN*DD;

  unsigned short* w1t  = (unsigned short*)d_ws;            // 512 KB
  unsigned short* w2b  = w1t + (size_t)FF*DD;              // 512 KB
  unsigned short* ewc  = w2b + (size_t)FF*DD;              // 64 KB (k-major chunks)
  unsigned short* ew2c = ewc + (size_t)256*128;            // 8 KB
  unsigned short* gw   = ew2c + (size_t)32*128;            // 192 KB
  unsigned short* tailf= gw + (size_t)3*32768;             // 8 KB
  unsigned short* pwf  = tailf + 4096;                     // 8 KB
  unsigned short* aggmf= pwf + 4096;                       // 4 KB

  hipLaunchKernelGGL(wconv_kernel, dim3(1024), dim3(256), 0, stream,
                     fw1, fw2, ew1, ew2, rw, uw, cw, pw, agg,
                     w1t, w2b, ewc, ew2c, gw, tailf, pwf, aggmf);
  hipLaunchKernelGGL(edge_mfma_kernel, dim3(NB/2), dim3(512), 0, stream,
                     nf, ea, src, tgt, eb1, eb2, pb, ewc, ew2c, tailf, pwf, aggmf,
                     g1, be1, out_em, out_x);
  hipLaunchKernelGGL(gate_mfma_kernel, dim3(NB*NN/64), dim3(256), 0, stream,
                     nf, rb, ub, cbv, g1, be1, gw, out_x);
  hipLaunchKernelGGL(ffn_mfma_kernel, dim3(NB*NN/128), dim3(512), 0, stream,
                     out_x, g2, be2, fb1, fb2, w1t, w2b);
}

// Round 16
// 300.219 us; speedup vs baseline: 1.2317x; 1.2317x over previous
//
#include <hip/hip_runtime.h>
#include <math.h>

#define NB 4096
#define NN 22
#define NE 42
#define DD 128
#define ED2 32
#define HH 128     // 4*ED
#define FF 2048
#define HCHUNKS 32 // FF/64

typedef float f32x4 __attribute__((ext_vector_type(4)));
typedef short s16x8 __attribute__((ext_vector_type(8)));

__device__ __forceinline__ float sigmoidf_(float x){ return 1.f/(1.f+__expf(-x)); }

__device__ __forceinline__ unsigned short f2bf(float f){
  unsigned u = __float_as_uint(f);
  u += 0x7fffu + ((u >> 16) & 1u);
  return (unsigned short)(u >> 16);
}
__device__ __forceinline__ float bf2f(unsigned short h){
  return __uint_as_float(((unsigned)h) << 16);
}
// gelu(x) = x*p/(p+1) = x - x/(p+1), p = exp(1.5957691*(x+0.044715 x^3))
__device__ __forceinline__ float gelu_f(float x){
  float x2 = x*x;
  float inner = fmaf(0.044715f*x2, x, x);
  float p = __builtin_amdgcn_exp2f(2.3022085f*inner);
  float t = __builtin_amdgcn_rcpf(p + 1.f);
  return fmaf(-x, t, x);
}

// ---- async global->LDS staging (zero VGPR footprint) ----
__device__ __forceinline__ void gld16(const void* g, void* l){
  __builtin_amdgcn_global_load_lds((__attribute__((address_space(1))) void*)g,
                                   (__attribute__((address_space(3))) void*)l, 16, 0, 0);
}
// stage BYTES from gbase to lbase; NW waves; BYTES % (NW*1024) == 0
template<int BYTES, int NW>
__device__ __forceinline__ void stage_lds(void* lbase, const void* gbase, int wave, int lane){
  const int per = BYTES / NW;
  const int ni  = per / 1024;
  const char* g = (const char*)gbase + wave*per + lane*16;
  char* l = (char*)lbase + wave*per;
  #pragma unroll
  for (int i=0;i<ni;i++) gld16(g + i*1024, l + i*1024);
}

#define S_VMCNT(N) { asm volatile("s_waitcnt vmcnt(" #N ")" ::: "memory"); __builtin_amdgcn_sched_barrier(0); }
#define S_LGKM0()  { asm volatile("s_waitcnt lgkmcnt(0)" ::: "memory"); __builtin_amdgcn_sched_barrier(0); }
#define RAW_BAR()  { asm volatile("s_waitcnt lgkmcnt(0)" ::: "memory"); __builtin_amdgcn_sched_barrier(0); __builtin_amdgcn_s_barrier(); __builtin_amdgcn_sched_barrier(0); }

// fragment-major index (u16 units) within a [C cols][128 k] bf16 tile
__device__ __forceinline__ int fragidx128(int c, int k){
  return ((c>>4)*4 + (k>>5))*512 + (((k>>3)&3)*16 + (c&15))*8 + (k&7);
}
__device__ __forceinline__ int fragidx64(int c, int k){  // k in [0,64)
  return ((c>>4)*2 + (k>>5))*512 + (((k>>3)&3)*16 + (c&15))*8 + (k&7);
}

// ---------------- K0: weight prep (fp32 -> bf16, fragment-major) ----------------
__global__ __launch_bounds__(256) void wconv_kernel(
    const float* __restrict__ fw1, const float* __restrict__ fw2,
    const float* __restrict__ ew1, const float* __restrict__ ew2,
    const float* __restrict__ rw, const float* __restrict__ uw, const float* __restrict__ cw,
    const float* __restrict__ pw, const float* __restrict__ aggm,
    unsigned short* __restrict__ w1t, unsigned short* __restrict__ w2b,
    unsigned short* __restrict__ ewc, unsigned short* __restrict__ ew2c,
    unsigned short* __restrict__ gw,
    unsigned short* __restrict__ tailf, unsigned short* __restrict__ pwf,
    unsigned short* __restrict__ aggmf)
{
  const int idx = blockIdx.x*256 + threadIdx.x;   // 0..262143
  {
    const int k = idx >> 11, j = idx & 2047;      // fw1 [128][2048]
    w1t[(j>>7)*16384 + fragidx128(j&127, k)] = f2bf(fw1[idx]);
  }
  {
    const int kg = idx >> 7, c = idx & 127;       // fw2 [2048][128] -> 16KB half-chunks (64 k rows)
    w2b[(kg>>6)*8192 + fragidx64(c, kg&63)] = f2bf(fw2[idx]);
  }
  if (idx < 32768) {
    // ewc2: k-major 16KB chunks: part (src/tgt) x khalf contiguous
    const int c2 = idx >> 7, k = idx & 127;
    const int part = c2 >> 7, c = c2 & 127;
    const float v = ew1[(part*128 + k)*DD + c];
    ewc[part*16384 + ((k>>5)*8 + (c>>4))*512 + (((k>>3)&3)*16 + (c&15))*8 + (k&7)] = f2bf(v);
  }
  if (idx < 4096) {
    const int m = idx & 31, k = idx >> 5;         // ew2 [128][32]
    ew2c[fragidx128(m, k)] = f2bf(ew2[k*ED2 + m]);
  }
  if (idx < 4096) {
    // tailf / pwf: B-frag [32 k][128 c], single k-step
    const int k = idx >> 7, c = idx & 127;
    const int u = (c>>4)*512 + ((k>>3)*16 + (c&15))*8 + (k&7);
    tailf[u] = f2bf(ew1[(256 + k)*DD + c]);
    pwf[u]  = f2bf(pw[k*DD + c]);
  }
  if (idx < 2048) {
    // aggmf: A-frag [32 n][64 e], zero-padded
    const int n = idx >> 6, e = idx & 63;
    const float v = (n < NN && e < NE) ? aggm[n*NE + e] : 0.f;
    aggmf[(n>>4)*1024 + (e>>5)*512 + (((e>>3)&3)*16 + (n&15))*8 + (e&7)] = f2bf(v);
  }
  if (idx < 98304) {
    const int gate = idx >> 15;
    const int rem  = idx & 32767;
    const int half = rem >> 14, c = (rem >> 7) & 127, k = rem & 127;
    const float* wsrc = (gate==0) ? rw : ((gate==1) ? uw : cw);
    const float v = wsrc[(half*128 + k)*128 + c];
    gw[gate*32768 + half*16384 + (k>>6)*8192 + fragidx64(c, k&63)] = f2bf(v);
  }
}

// ---------------- K1: all-MFMA edge path, 2 batches/block, 74.4KB LDS -> 2 blocks/CU ----------------
// Lifetime overlays (barrier-separated): s_h (24KB) overlays s_a (16KB, dead after
// round 3); pw restaged into s_w0 during em phase (w0 dead after round 4); proj
// rows + pack use s_h region (dead after em). Barrier-safe vmcnt(0) staging.
__global__ __launch_bounds__(512) void edge_mfma_kernel(
    const float* __restrict__ nf, const float* __restrict__ ea,
    const int* __restrict__ src, const int* __restrict__ tgt,
    const float* __restrict__ eb1, const float* __restrict__ eb2,
    const float* __restrict__ pb,
    const unsigned short* __restrict__ ewc2,
    const unsigned short* __restrict__ ew2c,
    const unsigned short* __restrict__ tailf,
    const unsigned short* __restrict__ pwf,
    const unsigned short* __restrict__ aggmf,
    const float* __restrict__ g1, const float* __restrict__ be1,
    float* __restrict__ out_em, float* __restrict__ out_x)
{
  const int t = threadIdx.x, lane = t & 63, wave = t >> 6;
  const int wv = wave & 3;               // intra-batch wave
  const int bb = wave >> 2;              // batch half
  const int b  = blockIdx.x*2 + bb;
  const int th = t & 255;                // intra-batch thread id

  __shared__ __align__(16) char s_lds[76160];
  unsigned short* s_w0  = (unsigned short*)(s_lds);            // 16KB ping (shared); pw here in em+
  unsigned short* s_w1  = (unsigned short*)(s_lds + 16384);    // 16KB pong (shared)
  unsigned short* s_emf = (unsigned short*)(s_lds + 16384 + bb*4096);  // 4KB/batch (overlay on s_w1)
  unsigned short* s_ew2 = (unsigned short*)(s_lds + 32768);    // 8KB (shared)
  unsigned short* s_agm = (unsigned short*)(s_lds + 40960);    // 4KB (shared)
  char*           s_a   = s_lds + 45056 + bb*8192;             // 8KB/batch (rounds 0-3)
  char*           s_h   = s_lds + 45056 + bb*12288;            // 12KB/batch (round4..em; then proj rows)
  unsigned short* s_eaf = (unsigned short*)(s_lds + 69632 + bb*3072);  // 3KB/batch
  unsigned short* s_agf = s_eaf;                               // 2KB overlay (eaf dead after round 4)
  int*            s_srcA= (int*)(s_lds + 75776);               // 48 ints (shared)
  int*            s_tgtA= (int*)(s_lds + 75968);               // 48 ints (shared)

  // ---- issue weight stages (ewc chunk0 + ew2 + agm), all waves ----
  stage_lds<16384,8>(s_w0, ewc2, wave, lane);
  stage_lds<8192,8>(s_ew2, ew2c, wave, lane);
  if (wave < 4) stage_lds<4096,4>(s_agm, aggmf, wave, lane);

  // ---- LN1 -> s_a bf16 XOR layout (rows 22..31 zero), per batch ----
  for (int r = wv; r < NN; r += 4) {
    const float* row = nf + ((size_t)b*NN + r)*DD;
    float x0 = row[lane], x1 = row[lane+64];
    float s = x0+x1, ss = x0*x0+x1*x1;
    #pragma unroll
    for (int off=32; off>=1; off>>=1) { s += __shfl_xor(s,off); ss += __shfl_xor(ss,off); }
    float m = s*(1.f/128.f);
    float inv = rsqrtf(ss*(1.f/128.f)-m*m + 1e-5f);
    float n0 = (x0-m)*inv*g1[lane]+be1[lane];
    float n1 = (x1-m)*inv*g1[lane+64]+be1[lane+64];
    char* base = s_a + r*256;
    const int sw = (r&7)<<4;
    *(unsigned short*)(base + ((lane*2)      ^ sw)) = f2bf(n0);
    *(unsigned short*)(base + (((lane+64)*2) ^ sw)) = f2bf(n1);
  }
  for (int i=th; i<640; i+=256) ((float*)(s_a + NN*256))[i] = 0.f;

  if (t < 48) { s_srcA[t] = (t < NE) ? src[t] : NN; s_tgtA[t] = (t < NE) ? tgt[t] : NN; }

  // ---- ea -> A-frag bf16 (rows 42..47 zero), per batch ----
  if (th < 168) {
    const int e = th >> 2, kb = th & 3;
    const float* p = ea + ((size_t)b*NE + e)*ED2 + kb*8;
    const float4 v0 = *(const float4*)p;
    const float4 v1 = *(const float4*)(p+4);
    unsigned long long lo = (unsigned long long)f2bf(v0.x) | ((unsigned long long)f2bf(v0.y)<<16)
                          | ((unsigned long long)f2bf(v0.z)<<32) | ((unsigned long long)f2bf(v0.w)<<48);
    unsigned long long hi = (unsigned long long)f2bf(v1.x) | ((unsigned long long)f2bf(v1.y)<<16)
                          | ((unsigned long long)f2bf(v1.z)<<32) | ((unsigned long long)f2bf(v1.w)<<48);
    unsigned long long* dst = (unsigned long long*)(s_eaf + (e>>4)*512 + (kb*16 + (e&15))*8);
    dst[0] = lo; dst[1] = hi;
  } else if (th < 192) {
    const int idx = th - 168;              // 0..23: zero rows 42..47
    const int kb = idx / 6, er = 10 + idx % 6;
    unsigned long long* dst = (unsigned long long*)(s_eaf + 2*512 + (kb*16 + er)*8);
    dst[0] = 0ull; dst[1] = 0ull;
  }

  __syncthreads();   // full drain (vmcnt+lgkm in every wave): s_w0 and all stages ready

  // ---- h = relu(gather(src)@Wsrc + gather(tgt)@Wtgt + ea@Wtail + eb1) ----
  const int frow = lane & 15;
  const int gsel = (lane >> 4) << 4;            // lane's 16B k-slot
  const int nt0 = wv*2;

  int rowS[3], rowT[3];
  #pragma unroll
  for (int mt=0; mt<3; ++mt){
    rowS[mt] = s_srcA[mt*16 + frow];
    rowT[mt] = s_tgtA[mt*16 + frow];
  }

  f32x4 hacc[3][2];
  #pragma unroll
  for (int mt=0; mt<3; ++mt){
    hacc[mt][0] = (f32x4){0.f,0.f,0.f,0.f};
    hacc[mt][1] = (f32x4){0.f,0.f,0.f,0.f};
  }

  #define HROUND(WCP, ROWS, KOFF) { \
    const unsigned short* wc_ = (WCP); \
    _Pragma("unroll") \
    for (int mt=0; mt<3; ++mt){ \
      const int r_ = (ROWS)[mt]; \
      const int sw_ = (r_&7)<<4; \
      const s16x8 a0 = *(const s16x8*)(s_a + r_*256 + (((KOFF) + gsel)^sw_)); \
      const s16x8 a1 = *(const s16x8*)(s_a + r_*256 + (((KOFF) + 64 + gsel)^sw_)); \
      _Pragma("unroll") \
      for (int ntl=0; ntl<2; ++ntl){ \
        const s16x8 b0 = *(const s16x8*)(wc_ + (    nt0+ntl)*512 + lane*8); \
        const s16x8 b1 = *(const s16x8*)(wc_ + (8 + nt0+ntl)*512 + lane*8); \
        hacc[mt][ntl] = __builtin_amdgcn_mfma_f32_16x16x32_bf16(a0, b0, hacc[mt][ntl], 0,0,0); \
        hacc[mt][ntl] = __builtin_amdgcn_mfma_f32_16x16x32_bf16(a1, b1, hacc[mt][ntl], 0,0,0); \
      } \
    } }

  // round 0: compute src k0..63 (s_w0); stage s_w1 overlapped, drain before BAR
  stage_lds<16384,8>(s_w1, ewc2 + 8192, wave, lane);
  HROUND(s_w0, rowS, 0);
  S_VMCNT(0);
  RAW_BAR();
  // round 1: src k64..127
  stage_lds<16384,8>(s_w0, ewc2 + 16384, wave, lane);
  HROUND(s_w1, rowS, 128);
  S_VMCNT(0);
  RAW_BAR();
  // round 2: tgt k0..63
  stage_lds<16384,8>(s_w1, ewc2 + 24576, wave, lane);
  HROUND(s_w0, rowT, 0);
  S_VMCNT(0);
  RAW_BAR();
  // round 3: tgt k64..127; stage tail (8KB) into s_w0
  stage_lds<8192,8>(s_w0, tailf, wave, lane);
  HROUND(s_w1, rowT, 128);
  S_VMCNT(0);
  RAW_BAR();   // after this bar: s_a dead (all HROUND reads done), s_h may be written
  #undef HROUND

  // round 4: ea@tail (s_w0 first 8KB) + zero both emf (s_w1 free) + h store
  { uint4 z; z.x=0u; z.y=0u; z.z=0u; z.w=0u; *(uint4*)(s_lds + 16384 + t*16) = z; }
  #pragma unroll
  for (int mt=0; mt<3; ++mt){
    const s16x8 ae = *(const s16x8*)(s_eaf + mt*512 + lane*8);
    #pragma unroll
    for (int ntl=0; ntl<2; ++ntl){
      const s16x8 bt = *(const s16x8*)(s_w0 + (nt0+ntl)*512 + lane*8);
      hacc[mt][ntl] = __builtin_amdgcn_mfma_f32_16x16x32_bf16(ae, bt, hacc[mt][ntl], 0,0,0);
    }
  }
  #pragma unroll
  for (int mt=0; mt<3; ++mt){
    #pragma unroll
    for (int ntl=0; ntl<2; ++ntl){
      const int c = (nt0+ntl)*16 + frow;
      const float e1 = eb1[c];
      #pragma unroll
      for (int reg=0; reg<4; ++reg){
        const int e = mt*16 + (lane>>4)*4 + reg;
        const float v = fmaxf(hacc[mt][ntl][reg] + e1, 0.f);
        *(unsigned short*)(s_h + e*256 + ((c*2) ^ ((e&7)<<4))) = (e < NE) ? f2bf(v) : (unsigned short)0;
      }
    }
  }
  RAW_BAR();   // after this bar: s_w0 dead (tail read done) -> pw restage target

  // ---- em = h @ ew2 + eb2 -> out_em (f32) + s_emf (B-frag bf16), per batch ----
  // stage pw into s_w0 (8KB) overlapped with em compute; drained before end bar
  stage_lds<8192,8>(s_w0, pwf, wave, lane);
  for (int id = wv; id < 6; id += 4) {
    const int mt = id >> 1, ntn = id & 1;
    f32x4 acc2 = (f32x4){0.f,0.f,0.f,0.f};
    #pragma unroll
    for (int ks=0; ks<4; ++ks){
      const s16x8 av = *(const s16x8*)(s_h + (mt*16 + frow)*256 + ((ks*64 + gsel) ^ ((frow&7)<<4)));
      const s16x8 bv = *(const s16x8*)(s_ew2 + (ntn*4+ks)*512 + lane*8);
      acc2 = __builtin_amdgcn_mfma_f32_16x16x32_bf16(av, bv, acc2, 0,0,0);
    }
    const int mc = ntn*16 + frow;
    const float bias = eb2[mc];
    #pragma unroll
    for (int reg=0; reg<4; ++reg){
      const int e = mt*16 + (lane>>4)*4 + reg;
      if (e < NE) {
        const float v = acc2[reg] + bias;
        out_em[((size_t)b*NE + e)*ED2 + mc] = v;
        s_emf[(mc>>4)*1024 + (e>>5)*512 + (((e>>3)&3)*16 + (mc&15))*8 + (e&7)] = f2bf(v);
      }
    }
  }
  S_VMCNT(0);   // pw arrived in every wave
  RAW_BAR();    // s_h (em reads) done -> proj may overwrite later; emf visible

  // ---- agg = aggm @ em (K padded to 64) -> s_agf (A-frag bf16), per batch ----
  {
    const int mt = wv >> 1, ntn = wv & 1;
    f32x4 acc3 = (f32x4){0.f,0.f,0.f,0.f};
    #pragma unroll
    for (int ks=0; ks<2; ++ks){
      const s16x8 av = *(const s16x8*)(s_agm + (mt*2+ks)*512 + lane*8);
      const s16x8 bv = *(const s16x8*)(s_emf + (ntn*2+ks)*512 + lane*8);
      acc3 = __builtin_amdgcn_mfma_f32_16x16x32_bf16(av, bv, acc3, 0,0,0);
    }
    const int mc = ntn*16 + frow;
    #pragma unroll
    for (int reg=0; reg<4; ++reg){
      const int n = mt*16 + (lane>>4)*4 + reg;
      s_agf[(n>>4)*512 + (((mc>>3)&3)*16 + (n&15))*8 + (mc&7)] = f2bf(acc3[reg]);
    }
  }
  RAW_BAR();

  // ---- proj = agg @ pw + pb -> s_h rows (bf16, swizzled), per batch ----
  const unsigned short* s_pw = (const unsigned short*)s_lds;   // pw now in s_w0
  #pragma unroll
  for (int ii=0; ii<4; ++ii){
    const int id = wv + ii*4;
    const int mt = id >> 3, nt = id & 7;
    const s16x8 av = *(const s16x8*)(s_agf + mt*512 + lane*8);
    const s16x8 bv = *(const s16x8*)(s_pw + nt*512 + lane*8);
    f32x4 a4 = __builtin_amdgcn_mfma_f32_16x16x32_bf16(av, bv, (f32x4){0.f,0.f,0.f,0.f}, 0,0,0);
    const int c = nt*16 + frow;
    const float pbv = pb[c];
    #pragma unroll
    for (int reg=0; reg<4; ++reg){
      const int n = mt*16 + (lane>>4)*4 + reg;
      *(unsigned short*)(s_h + n*256 + ((c*2) ^ ((n&7)<<4))) = f2bf(a4[reg] + pbv);
    }
  }
  RAW_BAR();

  // ---- pack proj rows into out_x fragment cells (16B stores), per batch ----
  for (int o=th; o<NN*16; o+=256){
    const int n = o>>4, cell = o&15;
    const int k0 = (cell>>2)*32 + (cell&3)*8;
    const uint4 v = *(const uint4*)(s_h + n*256 + ((k0*2) ^ ((n&7)<<4)));
    *(uint4*)((char*)out_x + (((size_t)b*NN + n)*512) + cell*16) = v;
  }
}

// ---------------- K2: gated update via MFMA (12-stage gld-lds ping-pong) ----------------
__global__ __launch_bounds__(256) void gate_mfma_kernel(
    const float* __restrict__ nf,
    const float* __restrict__ rb, const float* __restrict__ ub, const float* __restrict__ cbv,
    const float* __restrict__ g1, const float* __restrict__ be1,
    const unsigned short* __restrict__ gw,
    float* __restrict__ out_x)
{
  const int t=threadIdx.x, lane=t&63, wave=t>>6;
  const size_t row0 = (size_t)blockIdx.x * 64;
  const int wrow = wave*16;

  __shared__ __align__(16) unsigned short s_nb[8192];    // frag-major normed; becomes rc
  __shared__ __align__(16) unsigned short s_pb[8192];    // frag-major proj
  __shared__ __align__(16) unsigned short s_w[2][8192];  // 2x16KB ping-pong
  __shared__ float s_mean[64], s_inv[64];

  const char* gwb = (const char*)gw;

  stage_lds<16384,4>(s_w[0], gwb, wave, lane);   // stage 0 (latency under LN/proj copy)

  // proj copy: per-row cells -> fragment-major s_pb
  for (int i=t; i<1024; i+=256){
    const int r = i>>4, cell = i&15;
    ((uint4*)s_pb)[((r>>4)*4 + (cell>>2))*64 + (cell&3)*16 + (r&15)] =
      *((const uint4*)(out_x + (row0+r)*DD) + cell);
  }

  // LN1 -> s_nb fragment-major
  for (int r16=0; r16<16; ++r16){
    const int row = wrow + r16;
    const float* xr = nf + (row0+row)*DD;
    float x0=xr[lane], x1=xr[lane+64];
    float s=x0+x1, ss=x0*x0+x1*x1;
    #pragma unroll
    for (int off=32; off>=1; off>>=1){ s+=__shfl_xor(s,off); ss+=__shfl_xor(ss,off); }
    float m=s*(1.f/128.f);
    float inv=rsqrtf(ss*(1.f/128.f)-m*m+1e-5f);
    if (lane==0){ s_mean[row]=m; s_inv[row]=inv; }
    float n0=(x0-m)*inv*g1[lane]+be1[lane];
    float n1=(x1-m)*inv*g1[lane+64]+be1[lane+64];
    const int mt = row>>4, fr = row&15;
    const int ks = lane>>5, g = (lane>>3)&3, j = lane&7;
    s_nb[(mt*4+ks)*512   + (g*16+fr)*8 + j] = f2bf(n0);
    s_nb[(mt*4+ks+2)*512 + (g*16+fr)*8 + j] = f2bf(n1);
  }
  __syncthreads();   // drains stage0 + LDS writes

  s16x8 aN[4], aP[4];
  #pragma unroll
  for (int kk=0; kk<4; ++kk){
    aN[kk] = *(const s16x8*)(s_nb + (wave*4+kk)*512 + lane*8);
    aP[kk] = *(const s16x8*)(s_pb + (wave*4+kk)*512 + lane*8);
  }

  f32x4 accR[8], accU[8], accC[8];
  #pragma unroll
  for (int nt=0; nt<8; ++nt){
    const int col = nt*16 + (lane&15);
    accR[nt] = (f32x4){rb[col],rb[col],rb[col],rb[col]};
    accU[nt] = (f32x4){ub[col],ub[col],ub[col],ub[col]};
    accC[nt] = (f32x4){cbv[col],cbv[col],cbv[col],cbv[col]};
  }

  // Barrier-safe: each stage's loads are vmcnt(0)-drained by every wave before
  // the barrier that precedes its first read.
  #define GSTAGE(S, NEXT, ACC, A0, A1) { \
    if (NEXT) stage_lds<16384,4>(s_w[((S)+1)&1], gwb + ((S)+1)*16384, wave, lane); \
    unsigned short* sb = s_w[(S)&1]; \
    _Pragma("unroll") for (int nt=0;nt<8;++nt){ \
      const s16x8 b0 = *(const s16x8*)(sb + (nt*2+0)*512 + lane*8); \
      ACC[nt] = __builtin_amdgcn_mfma_f32_16x16x32_bf16(A0, b0, ACC[nt], 0,0,0); \
      const s16x8 b1 = *(const s16x8*)(sb + (nt*2+1)*512 + lane*8); \
      ACC[nt] = __builtin_amdgcn_mfma_f32_16x16x32_bf16(A1, b1, ACC[nt], 0,0,0); } \
    S_VMCNT(0); \
    RAW_BAR(); }

  GSTAGE(0, 1, accR, aN[0], aN[1]);
  GSTAGE(1, 1, accR, aN[2], aN[3]);
  GSTAGE(2, 1, accR, aP[0], aP[1]);
  GSTAGE(3, 1, accR, aP[2], aP[3]);

  // rc = sigmoid(R)*normed, in-place in s_nb (own wave's rows only)
  #pragma unroll
  for (int nt=0; nt<8; ++nt){
    #pragma unroll
    for (int reg=0; reg<4; ++reg){
      const float r_ = sigmoidf_(accR[nt][reg]);
      const int frA = (lane>>4)*4 + reg;
      const int ks = nt>>1, g = ((nt&1)<<1) | ((lane&15)>>3), j = lane&7;
      unsigned short* p = s_nb + (wave*4+ks)*512 + (g*16+frA)*8 + j;
      *p = f2bf(r_ * bf2f(*p));
    }
  }
  s16x8 aRC[4];
  #pragma unroll
  for (int kk=0; kk<4; ++kk)
    aRC[kk] = *(const s16x8*)(s_nb + (wave*4+kk)*512 + lane*8);

  GSTAGE(4, 1, accU, aN[0], aN[1]);
  GSTAGE(5, 1, accU, aN[2], aN[3]);
  GSTAGE(6, 1, accU, aP[0], aP[1]);
  GSTAGE(7, 1, accU, aP[2], aP[3]);
  GSTAGE(8, 1, accC, aRC[0], aRC[1]);
  GSTAGE(9, 1, accC, aRC[2], aRC[3]);
  GSTAGE(10, 1, accC, aP[0], aP[1]);
  GSTAGE(11, 0, accC, aP[2], aP[3]);
  #undef GSTAGE

  // combine: x = nf + (1-u)*normed + u*cand
  #pragma unroll
  for (int nt=0; nt<8; ++nt){
    const int col = nt*16 + (lane&15);
    const float gg = g1[col], bb = be1[col];
    #pragma unroll
    for (int reg=0; reg<4; ++reg){
      const int rowl = wrow + (lane>>4)*4 + reg;
      const size_t grow = row0 + rowl;
      const float u_ = sigmoidf_(accU[nt][reg]);
      const float cand = tanhf(accC[nt][reg]);
      const float nfv = nf[grow*DD + col];
      const float nv = (nfv - s_mean[rowl])*s_inv[rowl]*gg + bb;
      out_x[grow*DD + col] = nfv + (1.f-u_)*nv + u_*cand;
    }
  }
}

// ---------------- K3: LN2 + FFN, M=128, 2D wave split (rg x cg = 4x2) ----------------
// (r10/r12 version — best measured. One vmcnt(0) drain per hc.)
__global__ __launch_bounds__(512) void ffn_mfma_kernel(
    float* __restrict__ out_x,
    const float* __restrict__ g2, const float* __restrict__ be2,
    const float* __restrict__ fb1, const float* __restrict__ fb2,
    const unsigned short* __restrict__ w1t,
    const unsigned short* __restrict__ w2b)
{
  const int t = threadIdx.x, lane = t & 63, wave = t >> 6;
  const size_t row0 = (size_t)blockIdx.x * 128;
  const int wrow = wave * 16;
  const int rg = wave >> 1, cg = wave & 1;

  __shared__ __align__(16) unsigned short s_buf[2][16384];  // 2 x 32KB: [w1 16KB | w2 16KB]
  __shared__ __align__(16) unsigned short s_hid[8192];      // 16KB: [m 0..7][ks 0..1] x 512 u16

  // prologue: stage buf0 = {w1[0], w2[0]}
  stage_lds<16384,8>(s_buf[0],        w1t, wave, lane);
  stage_lds<16384,8>(s_buf[0] + 8192, w2b, wave, lane);

  // LN2 -> buf1 (32KB free at prologue): mtile m written by wave m at
  // buf1 + (m>>2)*8192 + ((m&3)*4+ks)*512
  for (int r16 = 0; r16 < 16; ++r16) {
    const int row = wrow + r16;               // row>>4 == wave
    const float* xr = out_x + (row0+row)*DD;
    float x0 = xr[lane], x1 = xr[lane+64];
    float s = x0+x1, ss = x0*x0+x1*x1;
    #pragma unroll
    for (int off=32; off>=1; off>>=1){ s+=__shfl_xor(s,off); ss+=__shfl_xor(ss,off); }
    float m = s*(1.f/128.f);
    float inv = rsqrtf(ss*(1.f/128.f)-m*m+1e-5f);
    float n0 = (x0-m)*inv*g2[lane]+be2[lane];
    float n1 = (x1-m)*inv*g2[lane+64]+be2[lane+64];
    const int fr = row&15;
    const int ks = lane>>5, g = (lane>>3)&3, j = lane&7;
    unsigned short* dst = s_buf[1] + (wave>>2)*8192;
    const int wv = wave & 3;
    dst[(wv*4+ks)*512   + (g*16+fr)*8 + j] = f2bf(n0);
    dst[(wv*4+ks+2)*512 + (g*16+fr)*8 + j] = f2bf(n1);
  }
  __syncthreads();   // drains buf0 stage + LN LDS writes (cross-wave lift next)

  const int frow = lane & 15;
  const int q = lane >> 4;       // 0..3

  // lift aN for mtiles m = rg*2 + mt (cross-wave reads; safe after syncthreads)
  s16x8 aN[2][4];
  #pragma unroll
  for (int mt=0; mt<2; ++mt){
    const int m = rg*2 + mt;
    const unsigned short* srcb = s_buf[1] + (m>>2)*8192;
    #pragma unroll
    for (int ks=0; ks<4; ++ks)
      aN[mt][ks] = *(const s16x8*)(srcb + ((m&3)*4+ks)*512 + lane*8);
  }
  RAW_BAR();   // all waves' aN lifted before buf1 is restaged (hc=0 stages buf1)

  // hid store base (u16 units): addr = hb + mt*1024 + nt*256
  // k_half = cg*32 + nt*16 + q*4 -> ks0=cg, g=nt*2+(q>>1), j0=(q&1)*4
  const int hb = (rg*4 + cg)*512 + (((q>>1)*16 + frow)*8) + (q&1)*4;

  f32x4 accO[2][4];
  #pragma unroll
  for (int mt=0; mt<2; ++mt)
    #pragma unroll
    for (int nt=0; nt<4; ++nt)
      accO[mt][nt] = (f32x4){0.f,0.f,0.f,0.f};

  for (int hc = 0; hc < HCHUNKS; ++hc) {
    const unsigned short* cur = s_buf[hc & 1];
    unsigned short* nxt = s_buf[(hc + 1) & 1];
    if (hc < HCHUNKS-1) {
      stage_lds<16384,8>(nxt,        w1t + (hc+1)*8192, wave, lane);
      stage_lds<16384,8>(nxt + 8192, w2b + (hc+1)*8192, wave, lane);
    }

    // mm1 transposed: acc1[mt][nt]: D col = data row (frow of mtile rg*2+mt),
    // D row = hid col q*4+reg within tile (cg*2+nt)
    f32x4 acc1[2][2];
    #pragma unroll
    for (int nt=0; nt<2; ++nt){
      const float4 bv = *(const float4*)(fb1 + hc*64 + cg*32 + nt*16 + (q<<2));
      acc1[0][nt] = (f32x4){bv.x, bv.y, bv.z, bv.w};
      acc1[1][nt] = acc1[0][nt];
    }
    #pragma unroll
    for (int nt=0; nt<2; ++nt){
      #pragma unroll
      for (int ks=0; ks<4; ++ks){
        const s16x8 ww = *(const s16x8*)(cur + ((cg*2+nt)*4+ks)*512 + lane*8);
        acc1[0][nt] = __builtin_amdgcn_mfma_f32_16x16x32_bf16(ww, aN[0][ks], acc1[0][nt], 0,0,0);
        acc1[1][nt] = __builtin_amdgcn_mfma_f32_16x16x32_bf16(ww, aN[1][ks], acc1[1][nt], 0,0,0);
      }
    }
    // gelu -> packed b64 stores into hid A-frag
    #pragma unroll
    for (int mt=0; mt<2; ++mt){
      #pragma unroll
      for (int nt=0; nt<2; ++nt){
        const float e0 = gelu_f(acc1[mt][nt][0]);
        const float e1 = gelu_f(acc1[mt][nt][1]);
        const float e2 = gelu_f(acc1[mt][nt][2]);
        const float e3 = gelu_f(acc1[mt][nt][3]);
        unsigned plo, phi;
        asm("v_cvt_pk_bf16_f32 %0, %1, %2" : "=v"(plo) : "v"(e0), "v"(e1));
        asm("v_cvt_pk_bf16_f32 %0, %1, %2" : "=v"(phi) : "v"(e2), "v"(e3));
        uint2 pk; pk.x = plo; pk.y = phi;
        *(uint2*)((char*)s_hid + (hb + mt*1024 + nt*256)*2) = pk;
      }
    }
    RAW_BAR();   // hid visible cross-wave (lgkm0+bar; staged vmcnt stays in flight)

    // mm2: rows rg*32..+31 x out cols cg*64..+63
    s16x8 aH[2][2];
    #pragma unroll
    for (int mt=0; mt<2; ++mt)
      #pragma unroll
      for (int ks=0; ks<2; ++ks)
        aH[mt][ks] = *(const s16x8*)(s_hid + ((rg*2+mt)*2+ks)*512 + lane*8);
    #pragma unroll
    for (int nt=0; nt<4; ++nt){
      #pragma unroll
      for (int ks=0; ks<2; ++ks){
        const s16x8 bb = *(const s16x8*)(cur + 8192 + ((cg*4+nt)*2+ks)*512 + lane*8);
        accO[0][nt] = __builtin_amdgcn_mfma_f32_16x16x32_bf16(aH[0][ks], bb, accO[0][nt], 0,0,0);
        accO[1][nt] = __builtin_amdgcn_mfma_f32_16x16x32_bf16(aH[1][ks], bb, accO[1][nt], 0,0,0);
      }
    }
    S_VMCNT(0);   // nxt stage arrived in every wave (before the barrier)
    RAW_BAR();    // cur free for restage; nxt visible; hid safe to overwrite
  }

  #pragma unroll
  for (int mt=0; mt<2; ++mt){
    #pragma unroll
    for (int nt=0; nt<4; ++nt){
      const int colg = cg*64 + nt*16 + frow;
      const float bias = fb2[colg];
      #pragma unroll
      for (int reg=0; reg<4; ++reg){
        const size_t row = row0 + rg*32 + mt*16 + q*4 + reg;
        const float xo = out_x[row*DD + colg];
        out_x[row*DD + colg] = xo + bias + accO[mt][nt][reg];
      }
    }
  }
}

extern "C" void kernel_launch(void* const* d_in, const int* in_sizes, int n_in,
                              void* d_out, int out_size, void* d_ws, size_t ws_size,
                              hipStream_t stream) {
  const float* nf  = (const float*)d_in[0];
  const float* ea  = (const float*)d_in[1];
  const float* agg = (const float*)d_in[2];
  const int*   src = (const int*)d_in[3];
  const int*   tgt = (const int*)d_in[4];
  const float* ew1 = (const float*)d_in[5];
  const float* eb1 = (const float*)d_in[6];
  const float* ew2 = (const float*)d_in[7];
  const float* eb2 = (const float*)d_in[8];
  const float* pw  = (const float*)d_in[9];
  const float* pb  = (const float*)d_in[10];
  const float* rw  = (const float*)d_in[11];
  const float* rb  = (const float*)d_in[12];
  const float* uw  = (const float*)d_in[13];
  const float* ub  = (const float*)d_in[14];
  const float* cw  = (const float*)d_in[15];
  const float* cbv = (const float*)d_in[16];
  const float* g1  = (const float*)d_in[17];
  const float* be1 = (const float*)d_in[18];
  const float* g2  = (const float*)d_in[19];
  const float* be2 = (const float*)d_in[20];
  const float* fw1 = (const float*)d_in[21];
  const float* fb1 = (const float*)d_in[22];
  const float* fw2 = (const float*)d_in[23];
  const float* fb2 = (const float*)d_in[24];

  float* out_x  = (float*)d_out;
  float* out_em = (float*)d_out + (size_t)NB*NN*DD;

  unsigned short* w1t  = (unsigned short*)d_ws;            // 512 KB
  unsigned short* w2b  = w1t + (size_t)FF*DD;              // 512 KB
  unsigned short* ewc  = w2b + (size_t)FF*DD;              // 64 KB (k-major chunks)
  unsigned short* ew2c = ewc + (size_t)256*128;            // 8 KB
  unsigned short* gw   = ew2c + (size_t)32*128;            // 192 KB
  unsigned short* tailf= gw + (size_t)3*32768;             // 8 KB
  unsigned short* pwf  = tailf + 4096;                     // 8 KB
  unsigned short* aggmf= pwf + 4096;                       // 4 KB

  hipLaunchKernelGGL(wconv_kernel, dim3(1024), dim3(256), 0, stream,
                     fw1, fw2, ew1, ew2, rw, uw, cw, pw, agg,
                     w1t, w2b, ewc, ew2c, gw, tailf, pwf, aggmf);
  hipLaunchKernelGGL(edge_mfma_kernel, dim3(NB/2), dim3(512), 0, stream,
                     nf, ea, src, tgt, eb1, eb2, pb, ewc, ew2c, tailf, pwf, aggmf,
                     g1, be1, out_em, out_x);
  hipLaunchKernelGGL(gate_mfma_kernel, dim3(NB*NN/64), dim3(256), 0, stream,
                     nf, rb, ub, cbv, g1, be1, gw, out_x);
  hipLaunchKernelGGL(ffn_mfma_kernel, dim3(NB*NN/128), dim3(512), 0, stream,
                     out_x, g2, be2, fb1, fb2, w1t, w2b);
}